// Round 6
// baseline (981.059 us; speedup 1.0000x reference)
//
#include <hip/hip_runtime.h>

constexpr int SEQ = 2048;
constexpr int HD  = 64;
constexpr int NH  = 8;
constexpr int NB  = 8;
constexpr int BM  = 64;
constexpr int BN  = 64;
constexpr int KST = 72;   // LDS row stride (shorts): 144 B = 9*16 -> b128-aligned
constexpr float INV_T = 0.125f;
constexpr float LOG2E = 1.4426950408889634f;

typedef __attribute__((ext_vector_type(8))) short bf16x8;
typedef __attribute__((ext_vector_type(8))) short s16x8;
typedef __attribute__((ext_vector_type(4))) short s16x4;
typedef __attribute__((ext_vector_type(4))) float f32x4;
typedef __attribute__((ext_vector_type(4))) unsigned u32x4;

__device__ __forceinline__ short f2bf(float f) {
  unsigned u = __builtin_bit_cast(unsigned, f);
  u += 0x7fffu + ((u >> 16) & 1u);   // RNE
  return (short)(u >> 16);
}
__device__ __forceinline__ float bf2f(short s) {
  unsigned u = ((unsigned)(unsigned short)s) << 16;
  return __builtin_bit_cast(float, u);
}
__device__ __forceinline__ float fast_exp2(float x) {
#if __has_builtin(__builtin_amdgcn_exp2f)
  return __builtin_amdgcn_exp2f(x);
#else
  return exp2f(x);
#endif
}

// ---------------- prep 1: K -> bf16 rows, V -> bf16 transposed [bh][d][j] ----------------
__global__ __launch_bounds__(256)
void prep_kv(const float* __restrict__ k, const float* __restrict__ v,
             unsigned short* __restrict__ kb, unsigned short* __restrict__ vt)
{
  __shared__ unsigned short t[HD * KST];
  const int bh = blockIdx.y, jt = blockIdx.x, tid = threadIdx.x;
  const size_t base = (size_t)bh * SEQ * HD + (size_t)jt * BN * HD;  // tile origin (elems)

  // K: tile is 4096 contiguous elems; thread converts 16 at 16*tid
  {
    const float* kp = k + base + 16 * tid;
    unsigned short ko[16];
    for (int e = 0; e < 4; ++e) {
      f32x4 x = *(const f32x4*)(kp + 4 * e);
      for (int c = 0; c < 4; ++c) ko[4 * e + c] = (unsigned short)f2bf(x[c]);
    }
    *(s16x8*)(kb + base + 16 * tid)     = *(const s16x8*)&ko[0];
    *(s16x8*)(kb + base + 16 * tid + 8) = *(const s16x8*)&ko[8];
  }
  // V: read rows coalesced, transpose via LDS (conflicts ok here; tiny kernel)
  {
    const float* vp = v + base + 16 * tid;
    const int j = tid >> 2, d0 = (tid & 3) * 16;
    for (int e = 0; e < 4; ++e) {
      f32x4 x = *(const f32x4*)(vp + 4 * e);
      for (int c = 0; c < 4; ++c) t[(d0 + 4 * e + c) * KST + j] = (unsigned short)f2bf(x[c]);
    }
  }
  __syncthreads();
  {
    const int d = tid >> 2, ch = tid & 3;
    const size_t ob = (size_t)bh * HD * SEQ + (size_t)d * SEQ + jt * BN + ch * 16;
    *(s16x8*)(vt + ob)     = *(const s16x8*)&t[d * KST + ch * 16];
    *(s16x8*)(vt + ob + 8) = *(const s16x8*)&t[d * KST + ch * 16 + 8];
  }
}

// ---------------- prep 2: pk[h][i][j] = (bf16(mask*log2e)<<16)|bf16(mask*pos*log2e) ----------------
// Plain row-major layout -> fully streaming reads AND writes (unlike R0's scatter order).
__global__ __launch_bounds__(256)
void prep_pk(const float* __restrict__ pos, const float* __restrict__ mask,
             unsigned* __restrict__ pk)
{
  const size_t w = (size_t)blockIdx.x * 256 + threadIdx.x;  // quad index
  const size_t base = w * 4;                                // linear elem in (h,i,j)
  const size_t ij = base & (size_t)(SEQ * SEQ - 1);         // (i,j) within plane (mask is (1,1,S,S))
  f32x4 m = *(const f32x4*)(mask + ij);
  f32x4 p = *(const f32x4*)(pos + base);
  u32x4 o;
#pragma unroll
  for (int c = 0; c < 4; ++c) {
    unsigned mb = (unsigned)(unsigned short)f2bf(m[c] * LOG2E);
    unsigned pb = (unsigned)(unsigned short)f2bf(m[c] * p[c] * LOG2E);
    o[c] = (mb << 16) | pb;
  }
  *(u32x4*)(pk + base) = o;
}

// ---------------- main fused attention (swapped-QK, reg-prefetched pk, high occupancy) ----------------
__global__ __launch_bounds__(256, 8)
void attn_main(const float* __restrict__ q, const unsigned short* __restrict__ kb,
               const unsigned short* __restrict__ vt,
               const unsigned* __restrict__ pk,
               float* __restrict__ out)
{
  __shared__ unsigned short lds_k[BN * KST];   // K tile; ALIASED as P after barrier-3
  __shared__ unsigned short lds_v[HD * KST];   // V^T tile

  // XCD-aware swizzle: 8 batch-siblings of a (h, i-tile) group sit at stride-8
  // consecutive ids -> same XCD -> pk L2/L3 reuse.
  const int n = blockIdx.x;                 // 0..2047, bijective decode
  const int x = n & 7, b = (n >> 3) & 7, G = n >> 6;
  const int g = G * 8 + x;                  // group = (h, it), 256 groups
  const int h = g >> 5, it = g & 31;
  const int bh = b * NH + h;
  const int i0 = it * BM;

  const int tid = threadIdx.x, wave = tid >> 6, lane = tid & 63;
  const int quad = lane >> 4, lq = lane & 15;

  // Q fragment (scaled by 1/8 before rounding: exact exponent shift).
  // Used as the *B* operand of the swapped QK^T mfma (identical frag layout).
  bf16x8 aq[2];
  {
    const float* qp = q + ((size_t)bh * SEQ + i0 + wave * 16 + lq) * HD + quad * 8;
    for (int k0 = 0; k0 < 2; ++k0) {
      f32x4 xv = *(const f32x4*)(qp + k0 * 32);
      f32x4 yv = *(const f32x4*)(qp + k0 * 32 + 4);
      for (int c = 0; c < 4; ++c) {
        aq[k0][c]     = f2bf(xv[c] * INV_T);
        aq[k0][4 + c] = f2bf(yv[c] * INV_T);
      }
    }
  }

  f32x4 oacc[4];
  for (int d = 0; d < 4; ++d) oacc[d] = (f32x4){0.f, 0.f, 0.f, 0.f};
  float lrun = 0.f;                         // per-lane: sum over j for i = (wave*16+lq)

  // staging addresses: thread covers 16 shorts of each 64x64 bf16 tile (2 x b128)
  const int lw = (tid >> 3) * KST + (tid & 7) * 8;
  const unsigned short* kgb = kb + (size_t)bh * SEQ * HD + 8 * tid;                          // + jt*4096, e*2048
  const unsigned short* vgb = vt + (size_t)bh * HD * SEQ + (tid >> 3) * SEQ + (tid & 7) * 8; // + jt*64, e*32*SEQ

  // this lane's softmax row (i); 4 consecutive j per lane after swap -> one u32x4
  const int irow = i0 + wave * 16 + lq;
  const unsigned* pkrow = pk + ((size_t)h * SEQ + irow) * SEQ + quad * 4;

  unsigned short* lds_p = lds_k;            // alias: P overwrites K tile after B3
  const int pbase = wave * (16 * KST);

  // ---- register prefetch state (one full jt-tile ahead) ----
  s16x8 kx0, kx1, vx0, vx1;                 // K/V staging for current tile
  u32x4 pk4[4];                             // packed coeffs for current tile

  // prologue: issue tile-0 loads; they land while we wait at the first barrier
  kx0 = *(const s16x8*)(kgb);
  kx1 = *(const s16x8*)(kgb + 2048);
  vx0 = *(const s16x8*)(vgb);
  vx1 = *(const s16x8*)(vgb + 32 * SEQ);
#pragma unroll
  for (int s = 0; s < 4; ++s) pk4[s] = *(const u32x4*)(pkrow + s * 16);

  for (int jt = 0; jt < SEQ / BN; ++jt) {
    const int jn = (jt + 1) & 31;                      // next tile, wrapped: always in-bounds
    __syncthreads();                                   // B1: prev iter's P/V readers done
    *(s16x8*)&lds_k[lw]            = kx0;              // (compiler waits vmcnt for kx/vx here)
    *(s16x8*)&lds_k[lw + 32 * KST] = kx1;
    *(s16x8*)&lds_v[lw]            = vx0;
    *(s16x8*)&lds_v[lw + 32 * KST] = vx1;
    __syncthreads();                                   // B2: staging visible

    // issue NEXT tile's staging loads now (WAR-safe: ds_writes above already
    // read the regs); they have the whole QK+softmax+PV phase to land.
    kx0 = *(const s16x8*)(kgb + jn * 4096);
    kx1 = *(const s16x8*)(kgb + jn * 4096 + 2048);
    vx0 = *(const s16x8*)(vgb + jn * 64);
    vx1 = *(const s16x8*)(vgb + jn * 64 + 32 * SEQ);

    // S^T = K (Q/8)^T : row = j (quad*4+r), col = i (lq).
    f32x4 sa[4];
#pragma unroll
    for (int s = 0; s < 4; ++s) sa[s] = (f32x4){0.f, 0.f, 0.f, 0.f};
#pragma unroll
    for (int k0 = 0; k0 < 2; ++k0)
#pragma unroll
      for (int s = 0; s < 4; ++s) {
        bf16x8 bk = *(const bf16x8*)&lds_k[(s * 16 + lq) * KST + k0 * 32 + quad * 8];
        sa[s] = __builtin_amdgcn_mfma_f32_16x16x32_bf16(bk, aq[k0], sa[s], 0, 0, 0);
      }
    __syncthreads();                                   // B3: all K reads done; P may overwrite

    // softmax: consume prefetched pk4, immediately reissue for next tile.
    const unsigned* pkn = pkrow + jn * 64;
#pragma unroll
    for (int s = 0; s < 4; ++s) {
      u32x4 uu = pk4[s];
      pk4[s] = *(const u32x4*)(pkn + s * 16);          // prefetch next tile
      s16x4 pb;
      float ps = 0.f;
#pragma unroll
      for (int r = 0; r < 4; ++r) {
        float mf = __builtin_bit_cast(float, uu[r] & 0xffff0000u);  // mask*log2e
        float mq = __builtin_bit_cast(float, uu[r] << 16);          // mask*pos*log2e
        float a  = fmaf(mf, sa[s][r], mq);
        float p  = fast_exp2(a);
        unsigned pu = __builtin_bit_cast(unsigned, p);
        pb[r] = (short)(pu >> 16);
        ps += __builtin_bit_cast(float, pu & 0xffff0000u);  // sum the rounded p
      }
      lrun += ps;
      // P in natural [i][j] order: row lq, 4 consecutive j -> one b64
      *(s16x4*)&lds_p[pbase + lq * KST + s * 16 + quad * 4] = pb;
    }
    asm volatile("s_waitcnt lgkmcnt(0)" ::: "memory"); // wave-private P visibility

    // O += P V
#pragma unroll
    for (int k0 = 0; k0 < 2; ++k0) {
      bf16x8 ap = *(const bf16x8*)&lds_p[pbase + lq * KST + k0 * 32 + quad * 8];
#pragma unroll
      for (int d = 0; d < 4; ++d) {
        bf16x8 bv = *(const bf16x8*)&lds_v[(d * 16 + lq) * KST + k0 * 32 + quad * 8];
        oacc[d] = __builtin_amdgcn_mfma_f32_16x16x32_bf16(ap, bv, oacc[d], 0, 0, 0);
      }
    }
  }

  // row-sum finish: lanes {lq, lq+16, lq+32, lq+48} hold partials for row lq
  lrun += __shfl_xor(lrun, 16);
  lrun += __shfl_xor(lrun, 32);

#pragma unroll
  for (int r = 0; r < 4; ++r) {
    const float lv = __shfl(lrun, quad * 4 + r);       // total for row i = quad*4+r
    const float inv = 1.0f / lv;
    float* orow = out + ((size_t)bh * SEQ + i0 + wave * 16 + quad * 4 + r) * HD + lq;
#pragma unroll
    for (int d = 0; d < 4; ++d) orow[d * 16] = oacc[d][r] * inv;
  }
}

// ---------------- fallback (R1 kernel, used if ws too small) ----------------
__global__ __launch_bounds__(256, 2)
void attn_fused(const float* __restrict__ q, const float* __restrict__ kk,
                const float* __restrict__ vv, const float* __restrict__ pos,
                const float* __restrict__ mask, float* __restrict__ out)
{
  __shared__ short lds_k[BN * KST];
  __shared__ short lds_v[HD * KST];
  __shared__ short lds_p[4][16 * KST];
  const int bh = blockIdx.y, h = bh & (NH - 1);
  const int i0 = blockIdx.x * BM;
  const int tid = threadIdx.x, wave = tid >> 6, lane = tid & 63;
  const int quad = lane >> 4, lq = lane & 15;
  bf16x8 aq[2];
  {
    const float* qp = q + ((size_t)bh * SEQ + i0 + wave * 16 + lq) * HD + quad * 8;
    for (int k0 = 0; k0 < 2; ++k0) {
      f32x4 xv = *(const f32x4*)(qp + k0 * 32);
      f32x4 yv = *(const f32x4*)(qp + k0 * 32 + 4);
      for (int j = 0; j < 4; ++j) { aq[k0][j] = f2bf(xv[j] * INV_T); aq[k0][4 + j] = f2bf(yv[j] * INV_T); }
    }
  }
  f32x4 oacc[4];
  for (int d = 0; d < 4; ++d) oacc[d] = (f32x4){0.f, 0.f, 0.f, 0.f};
  float mrun[4] = {-INFINITY, -INFINITY, -INFINITY, -INFINITY};
  float lrun[4] = {0.f, 0.f, 0.f, 0.f};
  const size_t kvbase = (size_t)bh * SEQ * HD;
  for (int jt = 0; jt < SEQ / BN; ++jt) {
    const int j0 = jt * BN;
    __syncthreads();
    for (int e = 0; e < 4; ++e) {
      int idx = e * 256 + tid, j = idx >> 4, d4 = (idx & 15) << 2;
      f32x4 kf = *(const f32x4*)(kk + kvbase + (size_t)(j0 + j) * HD + d4);
      s16x4 ks;
      for (int c = 0; c < 4; ++c) ks[c] = f2bf(kf[c]);
      *(s16x4*)&lds_k[j * KST + d4] = ks;
      f32x4 vf = *(const f32x4*)(vv + kvbase + (size_t)(j0 + j) * HD + d4);
      for (int c = 0; c < 4; ++c) lds_v[(d4 + c) * KST + j] = f2bf(vf[c]);
    }
    __syncthreads();
    float mk[4][4], pz[4][4];
    for (int r = 0; r < 4; ++r) {
      const int i = i0 + wave * 16 + quad * 4 + r;
      const float* mrow = mask + (size_t)i * SEQ + j0 + lq;
      const float* prow = pos + ((size_t)h * SEQ + i) * SEQ + j0 + lq;
      for (int s = 0; s < 4; ++s) { mk[r][s] = mrow[s * 16]; pz[r][s] = prow[s * 16]; }
    }
    f32x4 sa[4];
    for (int s = 0; s < 4; ++s) sa[s] = (f32x4){0.f, 0.f, 0.f, 0.f};
    for (int k0 = 0; k0 < 2; ++k0)
      for (int s = 0; s < 4; ++s) {
        bf16x8 bk = *(const bf16x8*)&lds_k[(s * 16 + lq) * KST + k0 * 32 + quad * 8];
        sa[s] = __builtin_amdgcn_mfma_f32_16x16x32_bf16(aq[k0], bk, sa[s], 0, 0, 0);
      }
    for (int r = 0; r < 4; ++r) {
      float s0 = mk[r][0] * (sa[0][r] + pz[r][0]);
      float s1 = mk[r][1] * (sa[1][r] + pz[r][1]);
      float s2 = mk[r][2] * (sa[2][r] + pz[r][2]);
      float s3 = mk[r][3] * (sa[3][r] + pz[r][3]);
      float rm = fmaxf(fmaxf(s0, s1), fmaxf(s2, s3));
      for (int off = 1; off < 16; off <<= 1) rm = fmaxf(rm, __shfl_xor(rm, off));
      float mn = fmaxf(mrun[r], rm);
      float al = __expf(mrun[r] - mn);
      mrun[r] = mn;
      short p0 = f2bf(__expf(s0 - mn)), p1 = f2bf(__expf(s1 - mn));
      short p2 = f2bf(__expf(s2 - mn)), p3 = f2bf(__expf(s3 - mn));
      float ps = bf2f(p0) + bf2f(p1) + bf2f(p2) + bf2f(p3);
      for (int off = 1; off < 16; off <<= 1) ps += __shfl_xor(ps, off);
      lrun[r] = lrun[r] * al + ps;
      for (int d = 0; d < 4; ++d) oacc[d][r] *= al;
      short* pr = &lds_p[wave][(quad * 4 + r) * KST + lq];
      pr[0] = p0; pr[16] = p1; pr[32] = p2; pr[48] = p3;
    }
    asm volatile("s_waitcnt lgkmcnt(0)" ::: "memory");
    for (int k0 = 0; k0 < 2; ++k0) {
      bf16x8 ap = *(const bf16x8*)&lds_p[wave][lq * KST + k0 * 32 + quad * 8];
      for (int d = 0; d < 4; ++d) {
        bf16x8 bv = *(const bf16x8*)&lds_v[(d * 16 + lq) * KST + k0 * 32 + quad * 8];
        oacc[d] = __builtin_amdgcn_mfma_f32_16x16x32_bf16(ap, bv, oacc[d], 0, 0, 0);
      }
    }
  }
  for (int r = 0; r < 4; ++r) {
    const int i = i0 + wave * 16 + quad * 4 + r;
    const float inv = 1.0f / lrun[r];
    float* orow = out + ((size_t)bh * SEQ + i) * HD + lq;
    for (int d = 0; d < 4; ++d) orow[d * 16] = oacc[d][r] * inv;
  }
}

extern "C" void kernel_launch(void* const* d_in, const int* in_sizes, int n_in,
                              void* d_out, int out_size, void* d_ws, size_t ws_size,
                              hipStream_t stream) {
  const float* q    = (const float*)d_in[0];
  const float* k    = (const float*)d_in[1];
  const float* v    = (const float*)d_in[2];
  const float* pos  = (const float*)d_in[3];
  const float* mask = (const float*)d_in[4];
  float* out = (float*)d_out;

  const size_t kv_elems  = (size_t)NB * NH * SEQ * HD;         // 8,388,608
  const size_t kb_bytes  = kv_elems * 2;                       // 16 MB
  const size_t pk_dwords = (size_t)NH * SEQ * SEQ;             // 33,554,432
  const size_t need = 2 * kb_bytes + pk_dwords * 4;            // ~168 MB

  if (ws_size >= need) {
    unsigned short* kb = (unsigned short*)d_ws;
    unsigned short* vt = (unsigned short*)((char*)d_ws + kb_bytes);
    unsigned*       pk = (unsigned*)((char*)d_ws + 2 * kb_bytes);
    prep_kv<<<dim3(SEQ / BN, NB * NH), dim3(256), 0, stream>>>(k, v, kb, vt);
    prep_pk<<<dim3((int)(pk_dwords / 4 / 256)), dim3(256), 0, stream>>>(pos, mask, pk);
    attn_main<<<dim3(NB * NH * SEQ / BM), dim3(256), 0, stream>>>(q, kb, vt, pk, out);
  } else {
    attn_fused<<<dim3(SEQ / BM, NB * NH), dim3(256), 0, stream>>>(q, k, v, pos, mask, out);
  }
}

// Round 7
// 457.596 us; speedup vs baseline: 2.1439x; 2.1439x over previous
//
#include <hip/hip_runtime.h>

constexpr int SEQ = 2048;
constexpr int HD  = 64;
constexpr int NH  = 8;
constexpr int NB  = 8;
constexpr int BM  = 64;
constexpr int BN  = 64;
constexpr int KST = 72;   // LDS row stride (shorts): 144 B = 9*16 -> b128-aligned
constexpr float INV_T = 0.125f;
constexpr float LOG2E = 1.4426950408889634f;

typedef __attribute__((ext_vector_type(8))) short bf16x8;
typedef __attribute__((ext_vector_type(8))) short s16x8;
typedef __attribute__((ext_vector_type(4))) short s16x4;
typedef __attribute__((ext_vector_type(4))) float f32x4;
typedef __attribute__((ext_vector_type(4))) unsigned u32x4;

__device__ __forceinline__ short f2bf(float f) {
  unsigned u = __builtin_bit_cast(unsigned, f);
  u += 0x7fffu + ((u >> 16) & 1u);   // RNE
  return (short)(u >> 16);
}
__device__ __forceinline__ float bf2f(short s) {
  unsigned u = ((unsigned)(unsigned short)s) << 16;
  return __builtin_bit_cast(float, u);
}
__device__ __forceinline__ float fast_exp2(float x) {
#if __has_builtin(__builtin_amdgcn_exp2f)
  return __builtin_amdgcn_exp2f(x);
#else
  return exp2f(x);
#endif
}

// ---------------- prep 1: K -> bf16 rows, V -> bf16 transposed [bh][d][j] ----------------
__global__ __launch_bounds__(256)
void prep_kv(const float* __restrict__ k, const float* __restrict__ v,
             unsigned short* __restrict__ kb, unsigned short* __restrict__ vt)
{
  __shared__ unsigned short t[HD * KST];
  const int bh = blockIdx.y, jt = blockIdx.x, tid = threadIdx.x;
  const size_t base = (size_t)bh * SEQ * HD + (size_t)jt * BN * HD;  // tile origin (elems)

  // K: tile is 4096 contiguous elems; thread converts 16 at 16*tid
  {
    const float* kp = k + base + 16 * tid;
    unsigned short ko[16];
    for (int e = 0; e < 4; ++e) {
      f32x4 x = *(const f32x4*)(kp + 4 * e);
      for (int c = 0; c < 4; ++c) ko[4 * e + c] = (unsigned short)f2bf(x[c]);
    }
    *(s16x8*)(kb + base + 16 * tid)     = *(const s16x8*)&ko[0];
    *(s16x8*)(kb + base + 16 * tid + 8) = *(const s16x8*)&ko[8];
  }
  // V: read rows coalesced, transpose via LDS (conflicts ok here; tiny kernel)
  {
    const float* vp = v + base + 16 * tid;
    const int j = tid >> 2, d0 = (tid & 3) * 16;
    for (int e = 0; e < 4; ++e) {
      f32x4 x = *(const f32x4*)(vp + 4 * e);
      for (int c = 0; c < 4; ++c) t[(d0 + 4 * e + c) * KST + j] = (unsigned short)f2bf(x[c]);
    }
  }
  __syncthreads();
  {
    const int d = tid >> 2, ch = tid & 3;
    const size_t ob = (size_t)bh * HD * SEQ + (size_t)d * SEQ + jt * BN + ch * 16;
    *(s16x8*)(vt + ob)     = *(const s16x8*)&t[d * KST + ch * 16];
    *(s16x8*)(vt + ob + 8) = *(const s16x8*)&t[d * KST + ch * 16 + 8];
  }
}

// ---------------- prep 2: packed coeffs in swapped-QK consumption order ----------------
// pk dword D = ((g*32 + jt)*16 + ws)*256 + lane*4 + c   with g=h*32+it, ws=w*4+s,
// encoding (i = it*64 + w*16 + (lane&15), j = jt*64 + s*16 + (lane>>4)*4 + c):
//   hi16 = bf16(mask*log2e), lo16 = bf16(mask*pos*log2e)
// attn_main's softmax then reads ONE contiguous u32x4 per lane (1 KB per wave-instr).
// Reads here are 64B row-segments per quad-group -> fully-consumed cache lines.
__global__ __launch_bounds__(256)
void prep_pk(const float* __restrict__ pos, const float* __restrict__ mask,
             unsigned* __restrict__ pk)
{
  const int gjt = blockIdx.x;               // 0..8191
  const int g = gjt >> 5, jt = gjt & 31;
  const int h = g >> 5, it = g & 31;
  const int tid = threadIdx.x;
  const int lane = tid & 63, lq = lane & 15, quad = lane >> 4;
#pragma unroll
  for (int e = 0; e < 4; ++e) {
    const int ws = (tid >> 6) + 4 * e;      // 0..15
    const int w = ws >> 2, s = ws & 3;
    const int i = it * 64 + w * 16 + lq;
    const int j = jt * 64 + s * 16 + quad * 4;
    f32x4 m = *(const f32x4*)(mask + (size_t)i * SEQ + j);
    f32x4 p = *(const f32x4*)(pos + ((size_t)h * SEQ + i) * SEQ + j);
    u32x4 o;
#pragma unroll
    for (int c = 0; c < 4; ++c) {
      unsigned mb = (unsigned)(unsigned short)f2bf(m[c] * LOG2E);
      unsigned pb = (unsigned)(unsigned short)f2bf(m[c] * p[c] * LOG2E);
      o[c] = (mb << 16) | pb;
    }
    *(u32x4*)(pk + ((size_t)gjt * 16 + ws) * 256 + lane * 4) = o;
  }
}

// ---------------- main fused attention (swapped-QK, coalesced pk, NO long-lived regs) ----------------
__global__ __launch_bounds__(256, 8)
void attn_main(const float* __restrict__ q, const unsigned short* __restrict__ kb,
               const unsigned short* __restrict__ vt,
               const unsigned* __restrict__ pk,
               float* __restrict__ out)
{
  __shared__ unsigned short lds_k[BN * KST];   // K tile; ALIASED as P after barrier-3
  __shared__ unsigned short lds_v[HD * KST];   // V^T tile

  // Swizzle: 8 b-siblings of a (h,it) group at ids {slot, slot+8, ..., slot+56}
  // within one 64-id window -> same XCD (id%8 round-robin) AND temporally
  // adjacent -> pk slice fetched ~once per group (validated: R4/R5 1.3x fetch).
  const int n = blockIdx.x;                 // 0..2047, bijective decode
  const int x = n & 7, b = (n >> 3) & 7, G = n >> 6;
  const int g = G * 8 + x;                  // group = (h, it), 256 groups
  const int h = g >> 5, it = g & 31;
  const int bh = b * NH + h;
  const int i0 = it * BM;

  const int tid = threadIdx.x, wave = tid >> 6, lane = tid & 63;
  const int quad = lane >> 4, lq = lane & 15;

  // Q fragment (scaled by 1/8 before rounding: exact exponent shift).
  bf16x8 aq[2];
  {
    const float* qp = q + ((size_t)bh * SEQ + i0 + wave * 16 + lq) * HD + quad * 8;
    for (int k0 = 0; k0 < 2; ++k0) {
      f32x4 xv = *(const f32x4*)(qp + k0 * 32);
      f32x4 yv = *(const f32x4*)(qp + k0 * 32 + 4);
      for (int c = 0; c < 4; ++c) {
        aq[k0][c]     = f2bf(xv[c] * INV_T);
        aq[k0][4 + c] = f2bf(yv[c] * INV_T);
      }
    }
  }

  f32x4 oacc[4];
  for (int d = 0; d < 4; ++d) oacc[d] = (f32x4){0.f, 0.f, 0.f, 0.f};
  float lrun = 0.f;                         // per-lane: sum over j for i = (wave*16+lq)

  // staging addresses: thread covers 16 shorts of each 64x64 bf16 tile (2 x b128)
  const int lw = (tid >> 3) * KST + (tid & 7) * 8;
  const unsigned short* kgb = kb + (size_t)bh * SEQ * HD + 8 * tid;                          // + jt*4096, e*2048
  const unsigned short* vgb = vt + (size_t)bh * HD * SEQ + (tid >> 3) * SEQ + (tid & 7) * 8; // + jt*64, e*32*SEQ

  // coalesced pk base for this wave/lane (consumption-order layout)
  const unsigned* pkw = pk + (size_t)g * 131072 + wave * 1024 + lane * 4;

  unsigned short* lds_p = lds_k;            // alias: P overwrites K tile after B3
  const int pbase = wave * (16 * KST);

  for (int jt = 0; jt < SEQ / BN; ++jt) {
    __syncthreads();                                   // B1: prev iter's P/V readers done
    // K/V staging: short-lived regs (load -> immediately store). NO cross-loop
    // register state: keeps VGPR ~40 so the (256,8) occupancy holds (R6 lesson:
    // long-lived prefetch regs at 64-VGPR cap spilled 1.4 GB of scratch).
    s16x8 kx0 = *(const s16x8*)(kgb + jt * 4096);
    s16x8 kx1 = *(const s16x8*)(kgb + jt * 4096 + 2048);
    s16x8 vx0 = *(const s16x8*)(vgb + jt * 64);
    s16x8 vx1 = *(const s16x8*)(vgb + jt * 64 + 32 * SEQ);
    *(s16x8*)&lds_k[lw]            = kx0;
    *(s16x8*)&lds_k[lw + 32 * KST] = kx1;
    *(s16x8*)&lds_v[lw]            = vx0;
    *(s16x8*)&lds_v[lw + 32 * KST] = vx1;
    __syncthreads();                                   // B2: staging visible

    // S^T = K (Q/8)^T : row = j (quad*4+r), col = i (lq)
    f32x4 sa[4];
#pragma unroll
    for (int s = 0; s < 4; ++s) sa[s] = (f32x4){0.f, 0.f, 0.f, 0.f};
#pragma unroll
    for (int k0 = 0; k0 < 2; ++k0)
#pragma unroll
      for (int s = 0; s < 4; ++s) {
        bf16x8 bk = *(const bf16x8*)&lds_k[(s * 16 + lq) * KST + k0 * 32 + quad * 8];
        sa[s] = __builtin_amdgcn_mfma_f32_16x16x32_bf16(bk, aq[k0], sa[s], 0, 0, 0);
      }
    __syncthreads();                                   // B3: all K reads done; P may overwrite

    // softmax: ONE contiguous u32x4 per lane per s (1 KB per wave-instruction)
    const unsigned* pkj = pkw + jt * 4096;
#pragma unroll
    for (int s = 0; s < 4; ++s) {
      u32x4 uu = *(const u32x4*)(pkj + s * 256);
      s16x4 pb;
      float ps = 0.f;
#pragma unroll
      for (int r = 0; r < 4; ++r) {
        float mf = __builtin_bit_cast(float, uu[r] & 0xffff0000u);  // mask*log2e
        float mq = __builtin_bit_cast(float, uu[r] << 16);          // mask*pos*log2e
        float a  = fmaf(mf, sa[s][r], mq);
        float p  = fast_exp2(a);
        unsigned pu = __builtin_bit_cast(unsigned, p);
        pb[r] = (short)(pu >> 16);
        ps += __builtin_bit_cast(float, pu & 0xffff0000u);  // sum the rounded p
      }
      lrun += ps;
      // P in natural [i][j] order: row lq, 4 consecutive j -> one b64
      *(s16x4*)&lds_p[pbase + lq * KST + s * 16 + quad * 4] = pb;
    }
    asm volatile("s_waitcnt lgkmcnt(0)" ::: "memory"); // wave-private P visibility

    // O += P V
#pragma unroll
    for (int k0 = 0; k0 < 2; ++k0) {
      bf16x8 ap = *(const bf16x8*)&lds_p[pbase + lq * KST + k0 * 32 + quad * 8];
#pragma unroll
      for (int d = 0; d < 4; ++d) {
        bf16x8 bv = *(const bf16x8*)&lds_v[(d * 16 + lq) * KST + k0 * 32 + quad * 8];
        oacc[d] = __builtin_amdgcn_mfma_f32_16x16x32_bf16(ap, bv, oacc[d], 0, 0, 0);
      }
    }
  }

  // row-sum finish: lanes {lq, lq+16, lq+32, lq+48} hold partials for row lq
  lrun += __shfl_xor(lrun, 16);
  lrun += __shfl_xor(lrun, 32);

#pragma unroll
  for (int r = 0; r < 4; ++r) {
    const float lv = __shfl(lrun, quad * 4 + r);       // total for row i = quad*4+r
    const float inv = 1.0f / lv;
    float* orow = out + ((size_t)bh * SEQ + i0 + wave * 16 + quad * 4 + r) * HD + lq;
#pragma unroll
    for (int d = 0; d < 4; ++d) orow[d * 16] = oacc[d][r] * inv;
  }
}

// ---------------- fallback (R1 kernel, used if ws too small) ----------------
__global__ __launch_bounds__(256, 2)
void attn_fused(const float* __restrict__ q, const float* __restrict__ kk,
                const float* __restrict__ vv, const float* __restrict__ pos,
                const float* __restrict__ mask, float* __restrict__ out)
{
  __shared__ short lds_k[BN * KST];
  __shared__ short lds_v[HD * KST];
  __shared__ short lds_p[4][16 * KST];
  const int bh = blockIdx.y, h = bh & (NH - 1);
  const int i0 = blockIdx.x * BM;
  const int tid = threadIdx.x, wave = tid >> 6, lane = tid & 63;
  const int quad = lane >> 4, lq = lane & 15;
  bf16x8 aq[2];
  {
    const float* qp = q + ((size_t)bh * SEQ + i0 + wave * 16 + lq) * HD + quad * 8;
    for (int k0 = 0; k0 < 2; ++k0) {
      f32x4 xv = *(const f32x4*)(qp + k0 * 32);
      f32x4 yv = *(const f32x4*)(qp + k0 * 32 + 4);
      for (int j = 0; j < 4; ++j) { aq[k0][j] = f2bf(xv[j] * INV_T); aq[k0][4 + j] = f2bf(yv[j] * INV_T); }
    }
  }
  f32x4 oacc[4];
  for (int d = 0; d < 4; ++d) oacc[d] = (f32x4){0.f, 0.f, 0.f, 0.f};
  float mrun[4] = {-INFINITY, -INFINITY, -INFINITY, -INFINITY};
  float lrun[4] = {0.f, 0.f, 0.f, 0.f};
  const size_t kvbase = (size_t)bh * SEQ * HD;
  for (int jt = 0; jt < SEQ / BN; ++jt) {
    const int j0 = jt * BN;
    __syncthreads();
    for (int e = 0; e < 4; ++e) {
      int idx = e * 256 + tid, j = idx >> 4, d4 = (idx & 15) << 2;
      f32x4 kf = *(const f32x4*)(kk + kvbase + (size_t)(j0 + j) * HD + d4);
      s16x4 ks;
      for (int c = 0; c < 4; ++c) ks[c] = f2bf(kf[c]);
      *(s16x4*)&lds_k[j * KST + d4] = ks;
      f32x4 vf = *(const f32x4*)(vv + kvbase + (size_t)(j0 + j) * HD + d4);
      for (int c = 0; c < 4; ++c) lds_v[(d4 + c) * KST + j] = f2bf(vf[c]);
    }
    __syncthreads();
    float mk[4][4], pz[4][4];
    for (int r = 0; r < 4; ++r) {
      const int i = i0 + wave * 16 + quad * 4 + r;
      const float* mrow = mask + (size_t)i * SEQ + j0 + lq;
      const float* prow = pos + ((size_t)h * SEQ + i) * SEQ + j0 + lq;
      for (int s = 0; s < 4; ++s) { mk[r][s] = mrow[s * 16]; pz[r][s] = prow[s * 16]; }
    }
    f32x4 sa[4];
    for (int s = 0; s < 4; ++s) sa[s] = (f32x4){0.f, 0.f, 0.f, 0.f};
    for (int k0 = 0; k0 < 2; ++k0)
      for (int s = 0; s < 4; ++s) {
        bf16x8 bk = *(const bf16x8*)&lds_k[(s * 16 + lq) * KST + k0 * 32 + quad * 8];
        sa[s] = __builtin_amdgcn_mfma_f32_16x16x32_bf16(aq[k0], bk, sa[s], 0, 0, 0);
      }
    for (int r = 0; r < 4; ++r) {
      float s0 = mk[r][0] * (sa[0][r] + pz[r][0]);
      float s1 = mk[r][1] * (sa[1][r] + pz[r][1]);
      float s2 = mk[r][2] * (sa[2][r] + pz[r][2]);
      float s3 = mk[r][3] * (sa[3][r] + pz[r][3]);
      float rm = fmaxf(fmaxf(s0, s1), fmaxf(s2, s3));
      for (int off = 1; off < 16; off <<= 1) rm = fmaxf(rm, __shfl_xor(rm, off));
      float mn = fmaxf(mrun[r], rm);
      float al = __expf(mrun[r] - mn);
      mrun[r] = mn;
      short p0 = f2bf(__expf(s0 - mn)), p1 = f2bf(__expf(s1 - mn));
      short p2 = f2bf(__expf(s2 - mn)), p3 = f2bf(__expf(s3 - mn));
      float ps = bf2f(p0) + bf2f(p1) + bf2f(p2) + bf2f(p3);
      for (int off = 1; off < 16; off <<= 1) ps += __shfl_xor(ps, off);
      lrun[r] = lrun[r] * al + ps;
      for (int d = 0; d < 4; ++d) oacc[d][r] *= al;
      short* pr = &lds_p[wave][(quad * 4 + r) * KST + lq];
      pr[0] = p0; pr[16] = p1; pr[32] = p2; pr[48] = p3;
    }
    asm volatile("s_waitcnt lgkmcnt(0)" ::: "memory");
    for (int k0 = 0; k0 < 2; ++k0) {
      bf16x8 ap = *(const bf16x8*)&lds_p[wave][lq * KST + k0 * 32 + quad * 8];
      for (int d = 0; d < 4; ++d) {
        bf16x8 bv = *(const bf16x8*)&lds_v[(d * 16 + lq) * KST + k0 * 32 + quad * 8];
        oacc[d] = __builtin_amdgcn_mfma_f32_16x16x32_bf16(ap, bv, oacc[d], 0, 0, 0);
      }
    }
  }
  for (int r = 0; r < 4; ++r) {
    const int i = i0 + wave * 16 + quad * 4 + r;
    const float inv = 1.0f / lrun[r];
    float* orow = out + ((size_t)bh * SEQ + i) * HD + lq;
    for (int d = 0; d < 4; ++d) orow[d * 16] = oacc[d][r] * inv;
  }
}

extern "C" void kernel_launch(void* const* d_in, const int* in_sizes, int n_in,
                              void* d_out, int out_size, void* d_ws, size_t ws_size,
                              hipStream_t stream) {
  const float* q    = (const float*)d_in[0];
  const float* k    = (const float*)d_in[1];
  const float* v    = (const float*)d_in[2];
  const float* pos  = (const float*)d_in[3];
  const float* mask = (const float*)d_in[4];
  float* out = (float*)d_out;

  const size_t kv_elems  = (size_t)NB * NH * SEQ * HD;         // 8,388,608
  const size_t kb_bytes  = kv_elems * 2;                       // 16 MB
  const size_t pk_dwords = (size_t)NH * SEQ * SEQ;             // 33,554,432
  const size_t need = 2 * kb_bytes + pk_dwords * 4;            // ~168 MB

  if (ws_size >= need) {
    unsigned short* kb = (unsigned short*)d_ws;
    unsigned short* vt = (unsigned short*)((char*)d_ws + kb_bytes);
    unsigned*       pk = (unsigned*)((char*)d_ws + 2 * kb_bytes);
    prep_kv<<<dim3(SEQ / BN, NB * NH), dim3(256), 0, stream>>>(k, v, kb, vt);
    prep_pk<<<dim3(256 * 32), dim3(256), 0, stream>>>(pos, mask, pk);
    attn_main<<<dim3(NB * NH * SEQ / BM), dim3(256), 0, stream>>>(q, kb, vt, pk, out);
  } else {
    attn_fused<<<dim3(SEQ / BM, NB * NH), dim3(256), 0, stream>>>(q, k, v, pos, mask, out);
  }
}